// Round 8
// baseline (58.007 us; speedup 1.0000x reference)
//
#include <hip/hip_runtime.h>
#include <hip/hip_bf16.h>
#include <stdint.h>

// Problem constants
#define NVOX   884736      // 96*96*96 voxels per batch
#define NB     32          // batches
#define NPTS   512         // MAX_POINTS
#define CAP    4096        // worker candidate capacity per batch
#define THRV   0.9990234375f   // 1 - 2^-10 exactly; bits 0x3F7FC000; E[count]=864/batch
#define THR_TOP 0x3F7FFFFFu    // largest float bits < 1.0
#define BPB    216         // collect blocks per batch (4096 voxels each)
#define SLOT   64          // per-block candidate slots (lambda=4, overflow astronomically unlikely)
#define LBUF   80          // LDS staging capacity
#define NBUCK  128         // rank buckets (128 ulps each over the 16384-ulp threshold range)

#define C0c  0.28209479177387814f
#define C1c  0.4886025119029199f
#define C2c  0.6307831305050401f
#define SQ3c 1.7320508075688772f

typedef unsigned long long u64;
typedef unsigned int u32;

// ---------------------------------------------------------------------------
// Node 1: full scan of x. Each block scans 4096 voxels, writes candidates
// >= THRV into its FIXED slot region (plain stores, zero global atomics,
// nothing pre-zeroed). Cross-block visibility via the kernel-node boundary.
// ---------------------------------------------------------------------------
__global__ __launch_bounds__(256) void k_collect(const float* __restrict__ x,
                                                 u64* __restrict__ cand,
                                                 u32* __restrict__ counts) {
  const int b   = blockIdx.y;
  const int blk = blockIdx.x;
  const int tid = threadIdx.x;
  __shared__ u64 lbuf[LBUF];
  __shared__ int lcnt;
  if (tid == 0) lcnt = 0;
  __syncthreads();

  const float4* xb = reinterpret_cast<const float4*>(x + (size_t)b * NVOX);
  const int t0 = blk * 1024 + tid;                   // float4 index
  float4 q[4];
  #pragma unroll
  for (int it = 0; it < 4; ++it) q[it] = xb[t0 + it * 256];

  #pragma unroll
  for (int it = 0; it < 4; ++it) {
    const float4 qq = q[it];
    const u32 base = (u32)(t0 + it * 256) * 4u;
    if (qq.x >= THRV) { int p = atomicAdd(&lcnt, 1); if (p < LBUF) lbuf[p] = ((u64)__float_as_uint(qq.x) << 32) | (u64)(~(base      )); }
    if (qq.y >= THRV) { int p = atomicAdd(&lcnt, 1); if (p < LBUF) lbuf[p] = ((u64)__float_as_uint(qq.y) << 32) | (u64)(~(base + 1u)); }
    if (qq.z >= THRV) { int p = atomicAdd(&lcnt, 1); if (p < LBUF) lbuf[p] = ((u64)__float_as_uint(qq.z) << 32) | (u64)(~(base + 2u)); }
    if (qq.w >= THRV) { int p = atomicAdd(&lcnt, 1); if (p < LBUF) lbuf[p] = ((u64)__float_as_uint(qq.w) << 32) | (u64)(~(base + 3u)); }
  }
  __syncthreads();

  const int slot = b * BPB + blk;
  const int n = lcnt;
  const int wn = (n <= SLOT) ? n : SLOT;
  if (tid < wn) cand[(size_t)slot * SLOT + tid] = lbuf[tid];
  if (tid == 0) counts[slot] = (n <= SLOT) ? (u32)n : (u32)(SLOT + 1);  // >SLOT => exact fallback
}

// ---------------------------------------------------------------------------
// Node 2: ONE block per batch does everything else:
//   scan counts -> gather -> bucket rank-select (exact top-512, jax order)
//   -> center-of-mass -> 60-dim features (-> output) -> collapsed scalar
//   path (M built in-block) + float4-vectorized max-pool -> head MLP.
// R6's two hot spots are gone: rank loop is ~7 iters (buckets) instead of
// 885, pool matmul uses ds_read_b128 broadcasts instead of scalar reads.
// ---------------------------------------------------------------------------
__global__ __launch_bounds__(512) void k_worker(const float* __restrict__ x,
                                                const u64* __restrict__ cand,
                                                const u32* __restrict__ counts,
                                                const float* __restrict__ W1,
                                                const float* __restrict__ W2,
                                                const float* __restrict__ W3,
                                                const float* __restrict__ fc1w,
                                                const float* __restrict__ fc1b,
                                                const float* __restrict__ fc2w,
                                                const float* __restrict__ fc2b,
                                                float* __restrict__ dout) {
  const int b   = blockIdx.x;
  const int tid = threadIdx.x;

  // arena (64KB), phase-unioned:
  //   select : lk u64[CAP] @0 | lk2 u64[CAP] @32768   (also fallback hist in lk)
  //   feature: fs f32[512][20] @0 (40KB; overlaps lk/lk2 only after sk is final)
  __shared__ __align__(16) char arena[65536];
  __shared__ u64 sk[NPTS];
  __shared__ float Tm[16 * 64];
  __shared__ float Ms[16 * 128];
  __shared__ float pr[4][128];
  __shared__ float pl[128];
  __shared__ float hid[64];
  __shared__ u32 sA[256], sB[256];
  __shared__ u32 scnt[BPB], spref[BPB];
  __shared__ u32 bc[NBUCK], bbx[NBUCK], bp[NBUCK], bA[NBUCK], bB[NBUCK];
  __shared__ float rbuf[8][4];
  __shared__ float comv[4];
  __shared__ int sbad, sC;
  __shared__ u32 sthr;

  u64* lk  = reinterpret_cast<u64*>(arena);
  u64* lk2 = reinterpret_cast<u64*>(arena + 32768);

  // ---- collapsed scalar-path matrix M = (W1_0e/4)(W2_0e/sqrt32)(W3_0e/8)
  // (separate statics; no arena overlap, so it can run before select)
  const float s1c = 1.0f / (4.0f * sqrtf(32.0f));
  for (int e = tid; e < 16 * 64; e += 512) {
    const int u = e >> 6, j = e & 63;
    float s = 0.f;
    for (int k = 0; k < 32; ++k) s += W1[u * 32 + k] * W2[k * 64 + j];
    Tm[e] = s * s1c;
  }
  if (tid == 0) sbad = 0;
  __syncthreads();
  for (int e = tid; e < 16 * 128; e += 512) {
    const int u = e >> 7, vv = e & 127;
    float s = 0.f;
    for (int j = 0; j < 64; ++j) s += Tm[u * 64 + j] * W3[j * 128 + vv];
    Ms[e] = s * 0.125f;
  }

  // ---- parallel scan of per-slot counts ----
  u32 myc = 0;
  if (tid < 256) { myc = (tid < BPB) ? counts[b * BPB + tid] : 0u; sA[tid] = myc; }
  __syncthreads();
  if (tid < BPB && myc > SLOT) atomicOr(&sbad, 1);
  u32 *ssrc = sA, *sdst = sB;
  for (int off = 1; off < 256; off <<= 1) {
    if (tid < 256) sdst[tid] = ssrc[tid] + ((tid >= off) ? ssrc[tid - off] : 0u);
    __syncthreads();
    u32* t = ssrc; ssrc = sdst; sdst = t;
  }
  const int total = (int)ssrc[255];
  if (tid < BPB) { scnt[tid] = myc; spref[tid] = ssrc[tid] - myc; }
  __syncthreads();

  int C;
  if (!sbad && total >= NPTS && total <= CAP) {
    C = total;
    // gather slots into lk[0..C): 2 threads per slot
    for (int s = tid >> 1; s < BPB; s += 256) {
      const u32 c = scnt[s], p = spref[s];
      const u64* src = cand + (size_t)(b * BPB + s) * SLOT;
      for (u32 k = (u32)(tid & 1); k < c; k += 2) lk[p + k] = src[k];
    }
    __syncthreads();
  } else {
    // ---- exact fallback: fine histogram near 1.0 + re-collect ----
    u32* hist = reinterpret_cast<u32*>(lk);
    for (int i = tid; i < 4096; i += 512) hist[i] = 0u;
    __syncthreads();
    const u32* xb = reinterpret_cast<const u32*>(x) + (size_t)b * NVOX;
    for (int i = tid; i < NVOX; i += 512) {
      const u32 bits = xb[i];
      u32 key;
      if (bits >= 0x3F800000u) key = 0u;
      else { const u32 dd = THR_TOP - bits; key = dd >> 8; if (key > 4095u) key = 4095u; }
      atomicAdd(&hist[key], 1u);
    }
    __syncthreads();
    if (tid == 0) {
      u32 cum = 0; int kt = 4095;
      for (int k = 0; k < 4096; ++k) { cum += hist[k]; if (cum >= (u32)NPTS) { kt = k; break; } }
      sthr = (kt >= 4095) ? 0u : (0x3F800000u - ((u32)(kt + 1) << 8));
      sC = 0;
    }
    __syncthreads();
    const u32 thr = sthr;
    for (int i = tid; i < NVOX; i += 512) {
      const u32 bits = xb[i];
      if (bits >= thr) {
        const int p = atomicAdd(&sC, 1);
        if (p < CAP) lk[p] = ((u64)bits << 32) | (u64)(~(u32)i);
      }
    }
    __syncthreads();
    C = sC < CAP ? sC : CAP;
    __syncthreads();
  }

  // ---- bucket by value stripe (bucket 0 = largest values) ----
  if (tid < NBUCK) bc[tid] = 0u;
  __syncthreads();
  for (int i = tid; i < C; i += 512) {
    const u32 bits = (u32)(lk[i] >> 32);
    u32 bk = (THR_TOP - bits) >> 7; if (bk > (NBUCK - 1)) bk = NBUCK - 1;
    atomicAdd(&bc[bk], 1u);
  }
  __syncthreads();
  if (tid < NBUCK) bA[tid] = bc[tid];
  __syncthreads();
  u32 *bsrc = bA, *bdst = bB;
  for (int off = 1; off < NBUCK; off <<= 1) {
    if (tid < NBUCK) bdst[tid] = bsrc[tid] + ((tid >= off) ? bsrc[tid - off] : 0u);
    __syncthreads();
    u32* t = bsrc; bsrc = bdst; bdst = t;
  }
  if (tid < NBUCK) { bbx[tid] = bsrc[tid] - bc[tid]; bp[tid] = bsrc[tid] - bc[tid]; }
  __syncthreads();
  for (int i = tid; i < C; i += 512) {            // scatter into bucket order
    const u64 ki = lk[i];
    const u32 bits = (u32)(ki >> 32);
    u32 bk = (THR_TOP - bits) >> 7; if (bk > (NBUCK - 1)) bk = NBUCK - 1;
    const u32 p = atomicAdd(&bp[bk], 1u);
    lk2[p] = ki;
  }
  __syncthreads();
  for (int i = tid; i < C; i += 512) {            // exact rank within bucket
    const u64 ki = lk2[i];
    const u32 bits = (u32)(ki >> 32);
    u32 bk = (THR_TOP - bits) >> 7; if (bk > (NBUCK - 1)) bk = NBUCK - 1;
    const u32 lo = bbx[bk], hi = lo + bc[bk];
    int rank = (int)lo;
    for (u32 j = lo; j < hi; ++j) rank += (lk2[j] > ki) ? 1 : 0;
    if (rank < NPTS) sk[rank] = ki;
  }
  __syncthreads();   // sk final; lk/lk2 dead from here (fs may overwrite arena)

  const u64 key = sk[tid];
  const u32 bits = (u32)(key >> 32);
  const u32 idx  = ~((u32)key);
  const float v  = __uint_as_float(bits);
  const u32 z = idx / 9216u, rem = idx % 9216u, yy = rem / 96u, xw = rem % 96u;
  const float p0 = ((float)z  - 48.f) / 48.f;
  const float p1 = ((float)yy - 48.f) / 48.f;
  const float p2 = ((float)xw - 48.f) / 48.f;

  // ---- center of mass ----
  {
    float sv = v, s0 = p0 * v, s1 = p1 * v, s2 = p2 * v;
    for (int off = 32; off > 0; off >>= 1) {
      sv += __shfl_down(sv, off);
      s0 += __shfl_down(s0, off);
      s1 += __shfl_down(s1, off);
      s2 += __shfl_down(s2, off);
    }
    const int w = tid >> 6, ln = tid & 63;
    if (ln == 0) { rbuf[w][0] = sv; rbuf[w][1] = s0; rbuf[w][2] = s1; rbuf[w][3] = s2; }
    __syncthreads();
    if (tid == 0) {
      float tv = 0.f, t0s = 0.f, t1s = 0.f, t2s = 0.f;
      for (int wv = 0; wv < 8; ++wv) { tv += rbuf[wv][0]; t0s += rbuf[wv][1]; t1s += rbuf[wv][2]; t2s += rbuf[wv][3]; }
      const float dnm = fmaxf(tv, 1e-12f);
      comv[0] = t0s / dnm; comv[1] = t1s / dnm; comv[2] = t2s / dnm;
    }
    __syncthreads();
  }

  // ---- features (1 thread per point) ----
  float (*fs)[20] = reinterpret_cast<float(*)[20]>(arena);  // 40KB, 16B-aligned rows

  const float c0 = p0 - comv[0];
  const float c1 = p1 - comv[1];
  const float c2 = p2 - comv[2];
  const float r = fmaxf(sqrtf(c0 * c0 + c1 * c1 + c2 * c2), 1e-6f);
  const float inv = 1.0f / r;
  const float d0 = c0 * inv, d1 = c1 * inv, d2 = c2 * inv;
  const float v2 = v * v;
  const float rr2 = r * r;
  const float l1 = log1pf(r);
  const float er = expf(-r);
  const float sgv = 1.0f / (1.0f + expf(-v));
  const float sgr = 1.0f / (1.0f + expf(-r));

  float f[60];
  f[0]=v;      f[1]=r;      f[2]=C0c;     f[3]=v*r;
  f[4]=v2;     f[5]=l1;     f[6]=sqrtf(v + 1e-6f); f[7]=rr2;
  f[8]=v*C0c;  f[9]=er;     f[10]=v2*v;   f[11]=sqrtf(r);
  f[12]=v*l1;  f[13]=sgv;   f[14]=sgr;    f[15]=v*rr2;
  f[16]=c0;        f[17]=c1;        f[18]=c2;
  f[19]=c0*v;      f[20]=c1*v;      f[21]=c2*v;
  f[22]=C1c*d0;    f[23]=C1c*d1;    f[24]=C1c*d2;
  f[25]=c0*r;      f[26]=c1*r;      f[27]=c2*r;
  f[28]=d0;        f[29]=d1;        f[30]=d2;
  f[31]=d0*v;      f[32]=d1*v;      f[33]=d2*v;
  f[34]=c0*v2;     f[35]=c1*v2;     f[36]=c2*v2;
  f[37]=C1c*d0*r;  f[38]=C1c*d1*r;  f[39]=C1c*d2*r;
  const float t0 = C2c * (SQ3c * d0 * d2);
  const float t1 = C2c * (SQ3c * d0 * d1);
  const float t2_ = C2c * (d1 * d1 - 0.5f * (d0 * d0 + d2 * d2));
  const float t3 = C2c * (SQ3c * d1 * d2);
  const float t4 = C2c * (0.5f * SQ3c * (d2 * d2 - d0 * d0));
  f[40]=t0;     f[41]=t1;     f[42]=t2_;     f[43]=t3;     f[44]=t4;
  f[45]=t0*v;   f[46]=t1*v;   f[47]=t2_*v;   f[48]=t3*v;   f[49]=t4*v;
  f[50]=t0*r;   f[51]=t1*r;   f[52]=t2_*r;   f[53]=t3*r;   f[54]=t4*r;
  f[55]=t0*l1;  f[56]=t1*l1;  f[57]=t2_*l1;  f[58]=t3*l1;  f[59]=t4*l1;

  // feat output: d_out[16384 + (b*512 + n)*60 ...]
  float4* ob = reinterpret_cast<float4*>(dout + 16384 + ((size_t)b * NPTS + tid) * 60);
  #pragma unroll
  for (int k = 0; k < 15; ++k) ob[k] = make_float4(f[4*k], f[4*k+1], f[4*k+2], f[4*k+3]);

  #pragma unroll
  for (int k = 0; k < 4; ++k)
    *reinterpret_cast<float4*>(&fs[tid][k * 4]) = make_float4(f[4*k], f[4*k+1], f[4*k+2], f[4*k+3]);
  __syncthreads();

  // ---- pool: h3 = fs @ Ms, max over 512 points (float4 LDS broadcasts) ----
  const int g = tid >> 7, vv = tid & 127;
  float mreg[16];
  #pragma unroll
  for (int u = 0; u < 16; ++u) mreg[u] = Ms[u * 128 + vv];
  float pm = -3.4e38f;
  for (int n = g; n < NPTS; n += 4) {
    const float4 a0 = *reinterpret_cast<const float4*>(&fs[n][0]);
    const float4 a1 = *reinterpret_cast<const float4*>(&fs[n][4]);
    const float4 a2 = *reinterpret_cast<const float4*>(&fs[n][8]);
    const float4 a3 = *reinterpret_cast<const float4*>(&fs[n][12]);
    float acc = a0.x*mreg[0] + a0.y*mreg[1] + a0.z*mreg[2] + a0.w*mreg[3]
              + a1.x*mreg[4] + a1.y*mreg[5] + a1.z*mreg[6] + a1.w*mreg[7]
              + a2.x*mreg[8] + a2.y*mreg[9] + a2.z*mreg[10]+ a2.w*mreg[11]
              + a3.x*mreg[12]+ a3.y*mreg[13]+ a3.z*mreg[14]+ a3.w*mreg[15];
    pm = fmaxf(pm, acc);
  }
  pr[g][vv] = pm;
  __syncthreads();
  if (g == 0) pl[vv] = fmaxf(fmaxf(pr[0][vv], pr[1][vv]), fmaxf(pr[2][vv], pr[3][vv]));
  __syncthreads();

  // ---- head MLP ----
  if (tid < 64) {
    float sh = fc1b[tid];
    for (int u = 0; u < 128; ++u) sh += pl[u] * fc1w[u * 64 + tid];
    hid[tid] = fmaxf(sh, 0.f);
  }
  __syncthreads();
  float sl = fc2b[tid];
  for (int j = 0; j < 64; ++j) sl += hid[j] * fc2w[j * 512 + tid];
  dout[b * 512 + tid] = sl;
}

extern "C" void kernel_launch(void* const* d_in, const int* in_sizes, int n_in,
                              void* d_out, int out_size, void* d_ws, size_t ws_size,
                              hipStream_t stream) {
  const float* x    = (const float*)d_in[0];
  const float* W1   = (const float*)d_in[1];   // W1_0e (16,32)
  const float* W2   = (const float*)d_in[4];   // W2_0e (32,64)
  const float* W3   = (const float*)d_in[7];   // W3_0e (64,128)
  const float* fc1w = (const float*)d_in[8];
  const float* fc1b = (const float*)d_in[9];
  const float* fc2w = (const float*)d_in[10];
  const float* fc2b = (const float*)d_in[11];
  float* out = (float*)d_out;

  // workspace (~3.6 MB); every read location is rewritten earlier in the same
  // call -> no cross-replay state, poison-safe.
  uint8_t* ws = (uint8_t*)d_ws;
  u32* counts = (u32*)ws;                       // 6912 u32
  u64* cand   = (u64*)(ws + 0x10000);           // 6912*64*8 = 3.54 MB

  dim3 g1(BPB, NB);
  k_collect<<<g1, 256, 0, stream>>>(x, cand, counts);
  k_worker<<<NB, 512, 0, stream>>>(x, cand, counts, W1, W2, W3,
                                   fc1w, fc1b, fc2w, fc2b, out);
}

// Round 9
// 42.455 us; speedup vs baseline: 1.3663x; 1.3663x over previous
//
#include <hip/hip_runtime.h>
#include <hip/hip_bf16.h>
#include <stdint.h>

// Problem constants
#define NVOX   884736      // 96*96*96 voxels per batch
#define NB     32          // batches
#define NPTS   512         // MAX_POINTS
#define CAP    4096        // worker candidate capacity per batch
#define THRV   0.9990234375f   // 1 - 2^-10 exactly; bits 0x3F7FC000; E[count]=864/batch
#define THR_TOP 0x3F7FFFFFu    // largest float bits < 1.0
#define BPB    216         // collect blocks per batch (4096 voxels each)
#define SLOT   64          // per-block candidate slots (lambda=4, overflow astronomically unlikely)
#define LBUF   80          // LDS staging capacity
#define NBUCK  128         // rank buckets (128 ulps each over the 16384-ulp threshold range)

#define C0c  0.28209479177387814f
#define C1c  0.4886025119029199f
#define C2c  0.6307831305050401f
#define SQ3c 1.7320508075688772f

typedef unsigned long long u64;
typedef unsigned int u32;

// ---------------------------------------------------------------------------
// Node 1: full scan of x -> per-block fixed candidate slots (no atomics, no
// pre-zeroing). Block (0,0) additionally builds the collapsed scalar-path
// matrix M = (W1_0e/4)(W2_0e/sqrt32)(W3_0e/8) into ws — amortized under the
// 6912-block scan so it's wall-free, and kills k_featpool's per-block
// 131k-scalar-load M build (R7's last modeled inefficiency).
// ---------------------------------------------------------------------------
__global__ __launch_bounds__(256) void k_collect(const float* __restrict__ x,
                                                 u64* __restrict__ cand,
                                                 u32* __restrict__ counts,
                                                 const float* __restrict__ W1,
                                                 const float* __restrict__ W2,
                                                 const float* __restrict__ W3,
                                                 float* __restrict__ Mg) {
  const int b   = blockIdx.y;
  const int blk = blockIdx.x;
  const int tid = threadIdx.x;
  __shared__ u64 lbuf[LBUF];
  __shared__ float Tm[16 * 64];
  __shared__ int lcnt;
  if (tid == 0) lcnt = 0;
  __syncthreads();

  const float4* xb = reinterpret_cast<const float4*>(x + (size_t)b * NVOX);
  const int t0 = blk * 1024 + tid;                   // float4 index
  float4 q[4];
  #pragma unroll
  for (int it = 0; it < 4; ++it) q[it] = xb[t0 + it * 256];

  #pragma unroll
  for (int it = 0; it < 4; ++it) {
    const float4 qq = q[it];
    const u32 base = (u32)(t0 + it * 256) * 4u;
    if (qq.x >= THRV) { int p = atomicAdd(&lcnt, 1); if (p < LBUF) lbuf[p] = ((u64)__float_as_uint(qq.x) << 32) | (u64)(~(base      )); }
    if (qq.y >= THRV) { int p = atomicAdd(&lcnt, 1); if (p < LBUF) lbuf[p] = ((u64)__float_as_uint(qq.y) << 32) | (u64)(~(base + 1u)); }
    if (qq.z >= THRV) { int p = atomicAdd(&lcnt, 1); if (p < LBUF) lbuf[p] = ((u64)__float_as_uint(qq.z) << 32) | (u64)(~(base + 2u)); }
    if (qq.w >= THRV) { int p = atomicAdd(&lcnt, 1); if (p < LBUF) lbuf[p] = ((u64)__float_as_uint(qq.w) << 32) | (u64)(~(base + 3u)); }
  }
  __syncthreads();

  const int slot = b * BPB + blk;
  const int n = lcnt;
  const int wn = (n <= SLOT) ? n : SLOT;
  if (tid < wn) cand[(size_t)slot * SLOT + tid] = lbuf[tid];
  if (tid == 0) counts[slot] = (n <= SLOT) ? (u32)n : (u32)(SLOT + 1);  // >SLOT => exact fallback

  // ---- M build (one block only; visible to k_featpool 2 node-boundaries later)
  if (blk == 0 && b == 0) {
    const float s1c = 1.0f / (4.0f * sqrtf(32.0f));
    for (int e = tid; e < 16 * 64; e += 256) {
      const int u = e >> 6, j = e & 63;
      float s = 0.f;
      for (int k = 0; k < 32; ++k) s += W1[u * 32 + k] * W2[k * 64 + j];
      Tm[e] = s * s1c;
    }
    __syncthreads();
    for (int e = tid; e < 16 * 128; e += 256) {
      const int u = e >> 7, vv = e & 127;
      float s = 0.f;
      for (int j = 0; j < 64; ++j) s += Tm[u * 64 + j] * W3[j * 128 + vv];
      Mg[e] = s * 0.125f;
    }
  }
}

// ---------------------------------------------------------------------------
// Node 2: one block per batch. Parallel scan of counts -> gather -> bucket
// rank-select (exact top-512, jax order) -> sel + center-of-mass.
// Exact histogram fallback if the static threshold under/overflows.
// ---------------------------------------------------------------------------
__global__ __launch_bounds__(512) void k_select(const float* __restrict__ x,
                                                const u64* __restrict__ cand,
                                                const u32* __restrict__ counts,
                                                u64* __restrict__ sel,
                                                float* __restrict__ comvg) {
  const int b   = blockIdx.x;
  const int tid = threadIdx.x;

  __shared__ u64 lk[CAP];          // 32 KB (also the fallback histogram)
  __shared__ u64 lk2[CAP];         // 32 KB bucket-ordered keys
  __shared__ u64 sk[NPTS];
  __shared__ u32 sA[256], sB[256];
  __shared__ u32 scnt[BPB], spref[BPB];
  __shared__ u32 bc[NBUCK], bbx[NBUCK], bp[NBUCK], bA[NBUCK], bB[NBUCK];
  __shared__ float rbuf[8][4];
  __shared__ int sbad, sC;
  __shared__ u32 sthr;

  // ---- parallel scan of per-slot counts ----
  u32 myc = 0;
  if (tid == 0) sbad = 0;
  if (tid < 256) { myc = (tid < BPB) ? counts[b * BPB + tid] : 0u; sA[tid] = myc; }
  __syncthreads();
  if (tid < BPB && myc > SLOT) atomicOr(&sbad, 1);
  u32 *ssrc = sA, *sdst = sB;
  for (int off = 1; off < 256; off <<= 1) {
    if (tid < 256) sdst[tid] = ssrc[tid] + ((tid >= off) ? ssrc[tid - off] : 0u);
    __syncthreads();
    u32* t = ssrc; ssrc = sdst; sdst = t;
  }
  const int total = (int)ssrc[255];
  if (tid < BPB) { scnt[tid] = myc; spref[tid] = ssrc[tid] - myc; }
  __syncthreads();

  int C;
  if (!sbad && total >= NPTS && total <= CAP) {
    C = total;
    // gather slots into lk[0..C): 2 threads per slot
    for (int s = tid >> 1; s < BPB; s += 256) {
      const u32 c = scnt[s], p = spref[s];
      const u64* src = cand + (size_t)(b * BPB + s) * SLOT;
      for (u32 k = (u32)(tid & 1); k < c; k += 2) lk[p + k] = src[k];
    }
    __syncthreads();
  } else {
    // ---- exact fallback: fine histogram near 1.0 + re-collect ----
    u32* hist = reinterpret_cast<u32*>(lk);
    for (int i = tid; i < 4096; i += 512) hist[i] = 0u;
    __syncthreads();
    const u32* xb = reinterpret_cast<const u32*>(x) + (size_t)b * NVOX;
    for (int i = tid; i < NVOX; i += 512) {
      const u32 bits = xb[i];
      u32 key;
      if (bits >= 0x3F800000u) key = 0u;
      else { const u32 dd = THR_TOP - bits; key = dd >> 8; if (key > 4095u) key = 4095u; }
      atomicAdd(&hist[key], 1u);
    }
    __syncthreads();
    if (tid == 0) {
      u32 cum = 0; int kt = 4095;
      for (int k = 0; k < 4096; ++k) { cum += hist[k]; if (cum >= (u32)NPTS) { kt = k; break; } }
      sthr = (kt >= 4095) ? 0u : (0x3F800000u - ((u32)(kt + 1) << 8));
      sC = 0;
    }
    __syncthreads();
    const u32 thr = sthr;
    for (int i = tid; i < NVOX; i += 512) {
      const u32 bits = xb[i];
      if (bits >= thr) {
        const int p = atomicAdd(&sC, 1);
        if (p < CAP) lk[p] = ((u64)bits << 32) | (u64)(~(u32)i);
      }
    }
    __syncthreads();
    C = sC < CAP ? sC : CAP;
    __syncthreads();
  }

  // ---- bucket the keys by value stripe (bucket 0 = largest values) ----
  if (tid < NBUCK) bc[tid] = 0u;
  __syncthreads();
  for (int i = tid; i < C; i += 512) {
    const u32 bits = (u32)(lk[i] >> 32);
    u32 bk = (THR_TOP - bits) >> 7; if (bk > (NBUCK - 1)) bk = NBUCK - 1;
    atomicAdd(&bc[bk], 1u);
  }
  __syncthreads();
  if (tid < NBUCK) bA[tid] = bc[tid];
  __syncthreads();
  u32 *bsrc = bA, *bdst = bB;
  for (int off = 1; off < NBUCK; off <<= 1) {
    if (tid < NBUCK) bdst[tid] = bsrc[tid] + ((tid >= off) ? bsrc[tid - off] : 0u);
    __syncthreads();
    u32* t = bsrc; bsrc = bdst; bdst = t;
  }
  if (tid < NBUCK) { bbx[tid] = bsrc[tid] - bc[tid]; bp[tid] = bsrc[tid] - bc[tid]; }
  __syncthreads();
  for (int i = tid; i < C; i += 512) {            // scatter into bucket order
    const u64 ki = lk[i];
    const u32 bits = (u32)(ki >> 32);
    u32 bk = (THR_TOP - bits) >> 7; if (bk > (NBUCK - 1)) bk = NBUCK - 1;
    const u32 p = atomicAdd(&bp[bk], 1u);
    lk2[p] = ki;
  }
  __syncthreads();
  for (int i = tid; i < C; i += 512) {            // exact rank within bucket
    const u64 ki = lk2[i];
    const u32 bits = (u32)(ki >> 32);
    u32 bk = (THR_TOP - bits) >> 7; if (bk > (NBUCK - 1)) bk = NBUCK - 1;
    const u32 lo = bbx[bk], hi = lo + bc[bk];
    int rank = (int)lo;
    for (u32 j = lo; j < hi; ++j) rank += (lk2[j] > ki) ? 1 : 0;
    if (rank < NPTS) sk[rank] = ki;
  }
  __syncthreads();

  const u64 key = sk[tid];
  sel[(size_t)b * NPTS + tid] = key;

  // ---- center of mass over the selected 512 ----
  const u32 bits = (u32)(key >> 32);
  const u32 idx  = ~((u32)key);
  const float v  = __uint_as_float(bits);
  const u32 z = idx / 9216u, rem = idx % 9216u, yy = rem / 96u, xw = rem % 96u;
  const float p0 = ((float)z  - 48.f) / 48.f;
  const float p1 = ((float)yy - 48.f) / 48.f;
  const float p2 = ((float)xw - 48.f) / 48.f;
  float sv = v, s0 = p0 * v, s1 = p1 * v, s2 = p2 * v;
  for (int off = 32; off > 0; off >>= 1) {
    sv += __shfl_down(sv, off);
    s0 += __shfl_down(s0, off);
    s1 += __shfl_down(s1, off);
    s2 += __shfl_down(s2, off);
  }
  const int w = tid >> 6, ln = tid & 63;
  if (ln == 0) { rbuf[w][0] = sv; rbuf[w][1] = s0; rbuf[w][2] = s1; rbuf[w][3] = s2; }
  __syncthreads();
  if (tid == 0) {
    float tv = 0.f, t0s = 0.f, t1s = 0.f, t2s = 0.f;
    for (int wv = 0; wv < 8; ++wv) { tv += rbuf[wv][0]; t0s += rbuf[wv][1]; t1s += rbuf[wv][2]; t2s += rbuf[wv][3]; }
    const float dnm = fmaxf(tv, 1e-12f);
    comvg[b * 4 + 0] = t0s / dnm; comvg[b * 4 + 1] = t1s / dnm;
    comvg[b * 4 + 2] = t2s / dnm; comvg[b * 4 + 3] = 0.f;
  }
}

// ---------------------------------------------------------------------------
// Node 3: 8 blocks per batch, 64 points each. Copies precomputed M (8 KB)
// to LDS, computes 60-dim features (-> output) + partial max-pool -> ppart.
// ---------------------------------------------------------------------------
__global__ __launch_bounds__(512) void k_featpool(const u64* __restrict__ sel,
                                                  const float* __restrict__ comvg,
                                                  const float* __restrict__ Mg,
                                                  float* __restrict__ ppart,
                                                  float* __restrict__ dout) {
  const int p8  = blockIdx.x;
  const int b   = blockIdx.y;
  const int tid = threadIdx.x;
  __shared__ float Ms[16 * 128];
  __shared__ __align__(16) float fs[64][20];  // 80B rows: 16B-aligned float4 reads
  __shared__ float pr[4][128];

  for (int e = tid; e < 16 * 128; e += 512) Ms[e] = Mg[e];   // 4 coalesced loads/thread

  // ---- per-point features (8 threads per point compute redundantly) ----
  const int pl = tid >> 3, cg = tid & 7;
  const int gp = b * NPTS + p8 * 64 + pl;            // global point id
  const u64 key = sel[gp];
  const u32 bits = (u32)(key >> 32);
  const u32 idx  = ~((u32)key);
  const float v  = __uint_as_float(bits);
  const u32 z = idx / 9216u, rem = idx % 9216u, yy = rem / 96u, xw = rem % 96u;
  const float4 cm = reinterpret_cast<const float4*>(comvg)[b];
  const float c0 = ((float)z  - 48.f) / 48.f - cm.x;
  const float c1 = ((float)yy - 48.f) / 48.f - cm.y;
  const float c2 = ((float)xw - 48.f) / 48.f - cm.z;
  const float r = fmaxf(sqrtf(c0 * c0 + c1 * c1 + c2 * c2), 1e-6f);
  const float inv = 1.0f / r;
  const float d0 = c0 * inv, d1 = c1 * inv, d2 = c2 * inv;
  const float v2 = v * v;
  const float rr2 = r * r;
  const float l1 = log1pf(r);
  const float er = expf(-r);
  const float sgv = 1.0f / (1.0f + expf(-v));
  const float sgr = 1.0f / (1.0f + expf(-r));

  float f[60];
  f[0]=v;      f[1]=r;      f[2]=C0c;     f[3]=v*r;
  f[4]=v2;     f[5]=l1;     f[6]=sqrtf(v + 1e-6f); f[7]=rr2;
  f[8]=v*C0c;  f[9]=er;     f[10]=v2*v;   f[11]=sqrtf(r);
  f[12]=v*l1;  f[13]=sgv;   f[14]=sgr;    f[15]=v*rr2;
  f[16]=c0;        f[17]=c1;        f[18]=c2;
  f[19]=c0*v;      f[20]=c1*v;      f[21]=c2*v;
  f[22]=C1c*d0;    f[23]=C1c*d1;    f[24]=C1c*d2;
  f[25]=c0*r;      f[26]=c1*r;      f[27]=c2*r;
  f[28]=d0;        f[29]=d1;        f[30]=d2;
  f[31]=d0*v;      f[32]=d1*v;      f[33]=d2*v;
  f[34]=c0*v2;     f[35]=c1*v2;     f[36]=c2*v2;
  f[37]=C1c*d0*r;  f[38]=C1c*d1*r;  f[39]=C1c*d2*r;
  const float t0 = C2c * (SQ3c * d0 * d2);
  const float t1 = C2c * (SQ3c * d0 * d1);
  const float t2_ = C2c * (d1 * d1 - 0.5f * (d0 * d0 + d2 * d2));
  const float t3 = C2c * (SQ3c * d1 * d2);
  const float t4 = C2c * (0.5f * SQ3c * (d2 * d2 - d0 * d0));
  f[40]=t0;     f[41]=t1;     f[42]=t2_;     f[43]=t3;     f[44]=t4;
  f[45]=t0*v;   f[46]=t1*v;   f[47]=t2_*v;   f[48]=t3*v;   f[49]=t4*v;
  f[50]=t0*r;   f[51]=t1*r;   f[52]=t2_*r;   f[53]=t3*r;   f[54]=t4*r;
  f[55]=t0*l1;  f[56]=t1*l1;  f[57]=t2_*l1;  f[58]=t3*l1;  f[59]=t4*l1;

  // feat output: chunk k written by thread with cg == k&7 (compile-time f idx)
  float4* ob = reinterpret_cast<float4*>(dout + 16384 + (size_t)gp * 60);
  #pragma unroll
  for (int k = 0; k < 15; ++k)
    if ((k & 7) == cg) ob[k] = make_float4(f[4*k], f[4*k+1], f[4*k+2], f[4*k+3]);

  // stage the 16 scalar features to LDS (cg 0..3 write one float4 each)
  #pragma unroll
  for (int k = 0; k < 4; ++k)
    if (k == cg) *reinterpret_cast<float4*>(&fs[pl][k * 4]) =
        make_float4(f[4*k], f[4*k+1], f[4*k+2], f[4*k+3]);
  __syncthreads();

  // ---- partial pool: h3 = fs @ Ms, max over this block's 64 points ----
  const int g = tid >> 7, vv = tid & 127;
  float mreg[16];
  #pragma unroll
  for (int u = 0; u < 16; ++u) mreg[u] = Ms[u * 128 + vv];
  float pm = -3.4e38f;
  for (int n = g; n < 64; n += 4) {
    const float4 a0 = *reinterpret_cast<const float4*>(&fs[n][0]);
    const float4 a1 = *reinterpret_cast<const float4*>(&fs[n][4]);
    const float4 a2 = *reinterpret_cast<const float4*>(&fs[n][8]);
    const float4 a3 = *reinterpret_cast<const float4*>(&fs[n][12]);
    float acc = a0.x*mreg[0] + a0.y*mreg[1] + a0.z*mreg[2] + a0.w*mreg[3]
              + a1.x*mreg[4] + a1.y*mreg[5] + a1.z*mreg[6] + a1.w*mreg[7]
              + a2.x*mreg[8] + a2.y*mreg[9] + a2.z*mreg[10]+ a2.w*mreg[11]
              + a3.x*mreg[12]+ a3.y*mreg[13]+ a3.z*mreg[14]+ a3.w*mreg[15];
    pm = fmaxf(pm, acc);
  }
  pr[g][vv] = pm;
  __syncthreads();
  if (g == 0)
    ppart[((size_t)b * 8 + p8) * 128 + vv] =
        fmaxf(fmaxf(pr[0][vv], pr[1][vv]), fmaxf(pr[2][vv], pr[3][vv]));
}

// ---------------------------------------------------------------------------
// Node 4: reduce the 8 pooled partials per batch + head MLP -> logits.
// ---------------------------------------------------------------------------
__global__ __launch_bounds__(512) void k_head(const float* __restrict__ ppart,
                                              const float* __restrict__ fc1w,
                                              const float* __restrict__ fc1b,
                                              const float* __restrict__ fc2w,
                                              const float* __restrict__ fc2b,
                                              float* __restrict__ dout) {
  const int b = blockIdx.x;
  const int t = threadIdx.x;
  __shared__ float pl[128];
  __shared__ float hid[64];
  if (t < 128) {
    float m = -3.4e38f;
    #pragma unroll
    for (int k = 0; k < 8; ++k) m = fmaxf(m, ppart[((size_t)b * 8 + k) * 128 + t]);
    pl[t] = m;
  }
  __syncthreads();
  if (t < 64) {
    float sh = fc1b[t];
    for (int u = 0; u < 128; ++u) sh += pl[u] * fc1w[u * 64 + t];
    hid[t] = fmaxf(sh, 0.f);
  }
  __syncthreads();
  float sl = fc2b[t];
  for (int j = 0; j < 64; ++j) sl += hid[j] * fc2w[j * 512 + t];
  dout[b * 512 + t] = sl;
}

extern "C" void kernel_launch(void* const* d_in, const int* in_sizes, int n_in,
                              void* d_out, int out_size, void* d_ws, size_t ws_size,
                              hipStream_t stream) {
  const float* x    = (const float*)d_in[0];
  const float* W1   = (const float*)d_in[1];   // W1_0e (16,32)
  const float* W2   = (const float*)d_in[4];   // W2_0e (32,64)
  const float* W3   = (const float*)d_in[7];   // W3_0e (64,128)
  const float* fc1w = (const float*)d_in[8];
  const float* fc1b = (const float*)d_in[9];
  const float* fc2w = (const float*)d_in[10];
  const float* fc2b = (const float*)d_in[11];
  float* out = (float*)d_out;

  // workspace (~4.6 MB); every read location is rewritten earlier in the same
  // call -> no cross-replay state, poison-safe.
  uint8_t* ws = (uint8_t*)d_ws;
  u32*   counts = (u32*)ws;                     // 6912 u32
  u64*   cand   = (u64*)(ws + 0x10000);         // 6912*64*8 = 3.54 MB
  u64*   sel    = (u64*)(ws + 0x400000);        // 32*512*8 = 128 KB
  float* comv   = (float*)(ws + 0x420000);      // 32 float4
  float* ppart  = (float*)(ws + 0x421000);      // 32*8*128 f32 = 128 KB
  float* Mg     = (float*)(ws + 0x450000);      // 16*128 f32 = 8 KB

  dim3 g1(BPB, NB);
  k_collect<<<g1, 256, 0, stream>>>(x, cand, counts, W1, W2, W3, Mg);
  k_select<<<NB, 512, 0, stream>>>(x, cand, counts, sel, comv);
  dim3 g3(8, NB);
  k_featpool<<<g3, 512, 0, stream>>>(sel, comv, Mg, ppart, out);
  k_head<<<NB, 512, 0, stream>>>(ppart, fc1w, fc1b, fc2w, fc2b, out);
}

// Round 10
// 41.507 us; speedup vs baseline: 1.3975x; 1.0228x over previous
//
#include <hip/hip_runtime.h>
#include <hip/hip_bf16.h>
#include <stdint.h>

// Problem constants
#define NVOX   884736      // 96*96*96 voxels per batch
#define NB     32          // batches
#define NPTS   512         // MAX_POINTS
#define CAP    4096        // candidate capacity per batch
#define THRV   0.9990234375f   // 1 - 2^-10 exactly; bits 0x3F7FC000; E[count]=864/batch
#define THR_TOP 0x3F7FFFFFu    // largest float bits < 1.0
#define BPB    216         // collect blocks per batch (4096 voxels each)
#define SLOT   64          // per-block candidate slots (lambda=4, overflow astronomically unlikely)
#define LBUF   80          // LDS staging capacity
#define NBUCK  128         // rank buckets

#define C0c  0.28209479177387814f
#define C1c  0.4886025119029199f
#define C2c  0.6307831305050401f
#define SQ3c 1.7320508075688772f

typedef unsigned long long u64;
typedef unsigned int u32;

// ---------------------------------------------------------------------------
// Node 1: full scan of x -> per-block fixed candidate slots (no atomics, no
// pre-zeroing). Block (0,0) additionally builds the collapsed scalar-path
// matrix M = (W1_0e/4)(W2_0e/sqrt32)(W3_0e/8) into ws (wall-free under the
// 6912-block scan).
// ---------------------------------------------------------------------------
__global__ __launch_bounds__(256) void k_collect(const float* __restrict__ x,
                                                 u64* __restrict__ cand,
                                                 u32* __restrict__ counts,
                                                 const float* __restrict__ W1,
                                                 const float* __restrict__ W2,
                                                 const float* __restrict__ W3,
                                                 float* __restrict__ Mg) {
  const int b   = blockIdx.y;
  const int blk = blockIdx.x;
  const int tid = threadIdx.x;
  __shared__ u64 lbuf[LBUF];
  __shared__ float Tm[16 * 64];
  __shared__ int lcnt;
  if (tid == 0) lcnt = 0;
  __syncthreads();

  const float4* xb = reinterpret_cast<const float4*>(x + (size_t)b * NVOX);
  const int t0 = blk * 1024 + tid;                   // float4 index
  float4 q[4];
  #pragma unroll
  for (int it = 0; it < 4; ++it) q[it] = xb[t0 + it * 256];

  #pragma unroll
  for (int it = 0; it < 4; ++it) {
    const float4 qq = q[it];
    const u32 base = (u32)(t0 + it * 256) * 4u;
    if (qq.x >= THRV) { int p = atomicAdd(&lcnt, 1); if (p < LBUF) lbuf[p] = ((u64)__float_as_uint(qq.x) << 32) | (u64)(~(base      )); }
    if (qq.y >= THRV) { int p = atomicAdd(&lcnt, 1); if (p < LBUF) lbuf[p] = ((u64)__float_as_uint(qq.y) << 32) | (u64)(~(base + 1u)); }
    if (qq.z >= THRV) { int p = atomicAdd(&lcnt, 1); if (p < LBUF) lbuf[p] = ((u64)__float_as_uint(qq.z) << 32) | (u64)(~(base + 2u)); }
    if (qq.w >= THRV) { int p = atomicAdd(&lcnt, 1); if (p < LBUF) lbuf[p] = ((u64)__float_as_uint(qq.w) << 32) | (u64)(~(base + 3u)); }
  }
  __syncthreads();

  const int slot = b * BPB + blk;
  const int n = lcnt;
  const int wn = (n <= SLOT) ? n : SLOT;
  if (tid < wn) cand[(size_t)slot * SLOT + tid] = lbuf[tid];
  if (tid == 0) counts[slot] = (n <= SLOT) ? (u32)n : (u32)(SLOT + 1);  // >SLOT => exact fallback

  if (blk == 0 && b == 0) {
    const float s1c = 1.0f / (4.0f * sqrtf(32.0f));
    for (int e = tid; e < 16 * 64; e += 256) {
      const int u = e >> 6, j = e & 63;
      float s = 0.f;
      for (int k = 0; k < 32; ++k) s += W1[u * 32 + k] * W2[k * 64 + j];
      Tm[e] = s * s1c;
    }
    __syncthreads();
    for (int e = tid; e < 16 * 128; e += 256) {
      const int u = e >> 7, vv = e & 127;
      float s = 0.f;
      for (int j = 0; j < 64; ++j) s += Tm[u * 64 + j] * W3[j * 128 + vv];
      Mg[e] = s * 0.125f;
    }
  }
}

// ---------------------------------------------------------------------------
// Node 2: 8 blocks per batch (256 blocks = 1/CU). Each block REDUNDANTLY
// gathers all ~864 candidates of its batch and runs the full bucket
// rank-select + COM (redundancy is wall-free: CUs were idle), then computes
// 60-dim features (-> output) + partial max-pool for its own 64-point
// segment straight from LDS sk — no sel/comv global round-trip, one fewer
// node than R9. Exact histogram fallback preserved.
// ---------------------------------------------------------------------------
__global__ __launch_bounds__(512) void k_selfeat(const float* __restrict__ x,
                                                 const u64* __restrict__ cand,
                                                 const u32* __restrict__ counts,
                                                 const float* __restrict__ Mg,
                                                 float* __restrict__ ppart,
                                                 float* __restrict__ dout) {
  const int p8  = blockIdx.x;
  const int b   = blockIdx.y;
  const int tid = threadIdx.x;

  __shared__ u64 lk[CAP];          // 32 KB (also the fallback histogram)
  __shared__ u64 lk2[CAP];         // 32 KB bucket-ordered keys
  __shared__ u64 sk[NPTS];
  __shared__ u32 sA[256], sB[256];
  __shared__ u32 scnt[BPB], spref[BPB];
  __shared__ u32 bc[NBUCK], bbx[NBUCK], bp[NBUCK], bA[NBUCK], bB[NBUCK];
  __shared__ float rbuf[8][4];
  __shared__ float comv[4];
  __shared__ float Ms[16 * 128];
  __shared__ __align__(16) float fsb[64][20];
  __shared__ float pr[4][128];
  __shared__ int sbad, sC;
  __shared__ u32 sthr;

  for (int e = tid; e < 16 * 128; e += 512) Ms[e] = Mg[e];

  // ---- parallel scan of per-slot counts ----
  u32 myc = 0;
  if (tid == 0) sbad = 0;
  if (tid < 256) { myc = (tid < BPB) ? counts[b * BPB + tid] : 0u; sA[tid] = myc; }
  __syncthreads();
  if (tid < BPB && myc > SLOT) atomicOr(&sbad, 1);
  u32 *ssrc = sA, *sdst = sB;
  for (int off = 1; off < 256; off <<= 1) {
    if (tid < 256) sdst[tid] = ssrc[tid] + ((tid >= off) ? ssrc[tid - off] : 0u);
    __syncthreads();
    u32* t = ssrc; ssrc = sdst; sdst = t;
  }
  const int total = (int)ssrc[255];
  if (tid < BPB) { scnt[tid] = myc; spref[tid] = ssrc[tid] - myc; }
  __syncthreads();

  int C;
  if (!sbad && total >= NPTS && total <= CAP) {
    C = total;
    for (int s = tid >> 1; s < BPB; s += 256) {     // gather, 2 threads/slot
      const u32 c = scnt[s], p = spref[s];
      const u64* src = cand + (size_t)(b * BPB + s) * SLOT;
      for (u32 k = (u32)(tid & 1); k < c; k += 2) lk[p + k] = src[k];
    }
    __syncthreads();
  } else {
    // ---- exact fallback: fine histogram near 1.0 + re-collect ----
    u32* hist = reinterpret_cast<u32*>(lk);
    for (int i = tid; i < 4096; i += 512) hist[i] = 0u;
    __syncthreads();
    const u32* xb = reinterpret_cast<const u32*>(x) + (size_t)b * NVOX;
    for (int i = tid; i < NVOX; i += 512) {
      const u32 bits = xb[i];
      u32 key;
      if (bits >= 0x3F800000u) key = 0u;
      else { const u32 dd = THR_TOP - bits; key = dd >> 8; if (key > 4095u) key = 4095u; }
      atomicAdd(&hist[key], 1u);
    }
    __syncthreads();
    if (tid == 0) {
      u32 cum = 0; int kt = 4095;
      for (int k = 0; k < 4096; ++k) { cum += hist[k]; if (cum >= (u32)NPTS) { kt = k; break; } }
      sthr = (kt >= 4095) ? 0u : (0x3F800000u - ((u32)(kt + 1) << 8));
      sC = 0;
    }
    __syncthreads();
    const u32 thr = sthr;
    for (int i = tid; i < NVOX; i += 512) {
      const u32 bits = xb[i];
      if (bits >= thr) {
        const int p = atomicAdd(&sC, 1);
        if (p < CAP) lk[p] = ((u64)bits << 32) | (u64)(~(u32)i);
      }
    }
    __syncthreads();
    C = sC < CAP ? sC : CAP;
    __syncthreads();
  }

  // ---- bucket rank-select (exact top-512, jax order) ----
  if (tid < NBUCK) bc[tid] = 0u;
  __syncthreads();
  for (int i = tid; i < C; i += 512) {
    const u32 bits = (u32)(lk[i] >> 32);
    u32 bk = (THR_TOP - bits) >> 7; if (bk > (NBUCK - 1)) bk = NBUCK - 1;
    atomicAdd(&bc[bk], 1u);
  }
  __syncthreads();
  if (tid < NBUCK) bA[tid] = bc[tid];
  __syncthreads();
  u32 *bsrc = bA, *bdst = bB;
  for (int off = 1; off < NBUCK; off <<= 1) {
    if (tid < NBUCK) bdst[tid] = bsrc[tid] + ((tid >= off) ? bsrc[tid - off] : 0u);
    __syncthreads();
    u32* t = bsrc; bsrc = bdst; bdst = t;
  }
  if (tid < NBUCK) { bbx[tid] = bsrc[tid] - bc[tid]; bp[tid] = bsrc[tid] - bc[tid]; }
  __syncthreads();
  for (int i = tid; i < C; i += 512) {            // scatter into bucket order
    const u64 ki = lk[i];
    const u32 bits = (u32)(ki >> 32);
    u32 bk = (THR_TOP - bits) >> 7; if (bk > (NBUCK - 1)) bk = NBUCK - 1;
    const u32 p = atomicAdd(&bp[bk], 1u);
    lk2[p] = ki;
  }
  __syncthreads();
  for (int i = tid; i < C; i += 512) {            // exact rank within bucket
    const u64 ki = lk2[i];
    const u32 bits = (u32)(ki >> 32);
    u32 bk = (THR_TOP - bits) >> 7; if (bk > (NBUCK - 1)) bk = NBUCK - 1;
    const u32 lo = bbx[bk], hi = lo + bc[bk];
    int rank = (int)lo;
    for (u32 j = lo; j < hi; ++j) rank += (lk2[j] > ki) ? 1 : 0;
    if (rank < NPTS) sk[rank] = ki;
  }
  __syncthreads();

  // ---- center of mass over the selected 512 ----
  {
    const u64 key = sk[tid];
    const u32 bits = (u32)(key >> 32);
    const u32 idx  = ~((u32)key);
    const float v  = __uint_as_float(bits);
    const u32 z = idx / 9216u, rem = idx % 9216u, yy = rem / 96u, xw = rem % 96u;
    const float p0 = ((float)z  - 48.f) / 48.f;
    const float p1 = ((float)yy - 48.f) / 48.f;
    const float p2 = ((float)xw - 48.f) / 48.f;
    float sv = v, s0 = p0 * v, s1 = p1 * v, s2 = p2 * v;
    for (int off = 32; off > 0; off >>= 1) {
      sv += __shfl_down(sv, off);
      s0 += __shfl_down(s0, off);
      s1 += __shfl_down(s1, off);
      s2 += __shfl_down(s2, off);
    }
    const int w = tid >> 6, ln = tid & 63;
    if (ln == 0) { rbuf[w][0] = sv; rbuf[w][1] = s0; rbuf[w][2] = s1; rbuf[w][3] = s2; }
    __syncthreads();
    if (tid == 0) {
      float tv = 0.f, t0s = 0.f, t1s = 0.f, t2s = 0.f;
      for (int wv = 0; wv < 8; ++wv) { tv += rbuf[wv][0]; t0s += rbuf[wv][1]; t1s += rbuf[wv][2]; t2s += rbuf[wv][3]; }
      const float dnm = fmaxf(tv, 1e-12f);
      comv[0] = t0s / dnm; comv[1] = t1s / dnm; comv[2] = t2s / dnm;
    }
    __syncthreads();
  }

  // ---- features for THIS block's 64-point segment (8 threads/point) ----
  const int pl = tid >> 3, cg = tid & 7;
  const int gp = b * NPTS + p8 * 64 + pl;
  const u64 key = sk[p8 * 64 + pl];
  const u32 bits = (u32)(key >> 32);
  const u32 idx  = ~((u32)key);
  const float v  = __uint_as_float(bits);
  const u32 z = idx / 9216u, rem = idx % 9216u, yy = rem / 96u, xw = rem % 96u;
  const float c0 = ((float)z  - 48.f) / 48.f - comv[0];
  const float c1 = ((float)yy - 48.f) / 48.f - comv[1];
  const float c2 = ((float)xw - 48.f) / 48.f - comv[2];
  const float r = fmaxf(sqrtf(c0 * c0 + c1 * c1 + c2 * c2), 1e-6f);
  const float inv = 1.0f / r;
  const float d0 = c0 * inv, d1 = c1 * inv, d2 = c2 * inv;
  const float v2 = v * v;
  const float rr2 = r * r;
  const float l1 = log1pf(r);
  const float er = expf(-r);
  const float sgv = 1.0f / (1.0f + expf(-v));
  const float sgr = 1.0f / (1.0f + expf(-r));

  float f[60];
  f[0]=v;      f[1]=r;      f[2]=C0c;     f[3]=v*r;
  f[4]=v2;     f[5]=l1;     f[6]=sqrtf(v + 1e-6f); f[7]=rr2;
  f[8]=v*C0c;  f[9]=er;     f[10]=v2*v;   f[11]=sqrtf(r);
  f[12]=v*l1;  f[13]=sgv;   f[14]=sgr;    f[15]=v*rr2;
  f[16]=c0;        f[17]=c1;        f[18]=c2;
  f[19]=c0*v;      f[20]=c1*v;      f[21]=c2*v;
  f[22]=C1c*d0;    f[23]=C1c*d1;    f[24]=C1c*d2;
  f[25]=c0*r;      f[26]=c1*r;      f[27]=c2*r;
  f[28]=d0;        f[29]=d1;        f[30]=d2;
  f[31]=d0*v;      f[32]=d1*v;      f[33]=d2*v;
  f[34]=c0*v2;     f[35]=c1*v2;     f[36]=c2*v2;
  f[37]=C1c*d0*r;  f[38]=C1c*d1*r;  f[39]=C1c*d2*r;
  const float t0 = C2c * (SQ3c * d0 * d2);
  const float t1 = C2c * (SQ3c * d0 * d1);
  const float t2_ = C2c * (d1 * d1 - 0.5f * (d0 * d0 + d2 * d2));
  const float t3 = C2c * (SQ3c * d1 * d2);
  const float t4 = C2c * (0.5f * SQ3c * (d2 * d2 - d0 * d0));
  f[40]=t0;     f[41]=t1;     f[42]=t2_;     f[43]=t3;     f[44]=t4;
  f[45]=t0*v;   f[46]=t1*v;   f[47]=t2_*v;   f[48]=t3*v;   f[49]=t4*v;
  f[50]=t0*r;   f[51]=t1*r;   f[52]=t2_*r;   f[53]=t3*r;   f[54]=t4*r;
  f[55]=t0*l1;  f[56]=t1*l1;  f[57]=t2_*l1;  f[58]=t3*l1;  f[59]=t4*l1;

  // feat output: chunk k written by thread with cg == k&7
  float4* ob = reinterpret_cast<float4*>(dout + 16384 + (size_t)gp * 60);
  #pragma unroll
  for (int k = 0; k < 15; ++k)
    if ((k & 7) == cg) ob[k] = make_float4(f[4*k], f[4*k+1], f[4*k+2], f[4*k+3]);

  // stage the 16 scalar features to LDS (cg 0..3 write one float4 each)
  #pragma unroll
  for (int k = 0; k < 4; ++k)
    if (k == cg) *reinterpret_cast<float4*>(&fsb[pl][k * 4]) =
        make_float4(f[4*k], f[4*k+1], f[4*k+2], f[4*k+3]);
  __syncthreads();

  // ---- partial pool: h3 = fs @ Ms, max over this block's 64 points ----
  const int g = tid >> 7, vv = tid & 127;
  float mreg[16];
  #pragma unroll
  for (int u = 0; u < 16; ++u) mreg[u] = Ms[u * 128 + vv];
  float pm = -3.4e38f;
  for (int n = g; n < 64; n += 4) {
    const float4 a0 = *reinterpret_cast<const float4*>(&fsb[n][0]);
    const float4 a1 = *reinterpret_cast<const float4*>(&fsb[n][4]);
    const float4 a2 = *reinterpret_cast<const float4*>(&fsb[n][8]);
    const float4 a3 = *reinterpret_cast<const float4*>(&fsb[n][12]);
    float acc = a0.x*mreg[0] + a0.y*mreg[1] + a0.z*mreg[2] + a0.w*mreg[3]
              + a1.x*mreg[4] + a1.y*mreg[5] + a1.z*mreg[6] + a1.w*mreg[7]
              + a2.x*mreg[8] + a2.y*mreg[9] + a2.z*mreg[10]+ a2.w*mreg[11]
              + a3.x*mreg[12]+ a3.y*mreg[13]+ a3.z*mreg[14]+ a3.w*mreg[15];
    pm = fmaxf(pm, acc);
  }
  pr[g][vv] = pm;
  __syncthreads();
  if (g == 0)
    ppart[((size_t)b * 8 + p8) * 128 + vv] =
        fmaxf(fmaxf(pr[0][vv], pr[1][vv]), fmaxf(pr[2][vv], pr[3][vv]));
}

// ---------------------------------------------------------------------------
// Node 3: reduce the 8 pooled partials per batch + head MLP -> logits.
// ---------------------------------------------------------------------------
__global__ __launch_bounds__(512) void k_head(const float* __restrict__ ppart,
                                              const float* __restrict__ fc1w,
                                              const float* __restrict__ fc1b,
                                              const float* __restrict__ fc2w,
                                              const float* __restrict__ fc2b,
                                              float* __restrict__ dout) {
  const int b = blockIdx.x;
  const int t = threadIdx.x;
  __shared__ float pl[128];
  __shared__ float hid[64];
  if (t < 128) {
    float m = -3.4e38f;
    #pragma unroll
    for (int k = 0; k < 8; ++k) m = fmaxf(m, ppart[((size_t)b * 8 + k) * 128 + t]);
    pl[t] = m;
  }
  __syncthreads();
  if (t < 64) {
    float sh = fc1b[t];
    for (int u = 0; u < 128; ++u) sh += pl[u] * fc1w[u * 64 + t];
    hid[t] = fmaxf(sh, 0.f);
  }
  __syncthreads();
  float sl = fc2b[t];
  for (int j = 0; j < 64; ++j) sl += hid[j] * fc2w[j * 512 + t];
  dout[b * 512 + t] = sl;
}

extern "C" void kernel_launch(void* const* d_in, const int* in_sizes, int n_in,
                              void* d_out, int out_size, void* d_ws, size_t ws_size,
                              hipStream_t stream) {
  const float* x    = (const float*)d_in[0];
  const float* W1   = (const float*)d_in[1];   // W1_0e (16,32)
  const float* W2   = (const float*)d_in[4];   // W2_0e (32,64)
  const float* W3   = (const float*)d_in[7];   // W3_0e (64,128)
  const float* fc1w = (const float*)d_in[8];
  const float* fc1b = (const float*)d_in[9];
  const float* fc2w = (const float*)d_in[10];
  const float* fc2b = (const float*)d_in[11];
  float* out = (float*)d_out;

  // workspace (~3.8 MB); every read location is rewritten earlier in the same
  // call -> no cross-replay state, poison-safe.
  uint8_t* ws = (uint8_t*)d_ws;
  u32*   counts = (u32*)ws;                     // 6912 u32
  u64*   cand   = (u64*)(ws + 0x10000);         // 6912*64*8 = 3.54 MB
  float* ppart  = (float*)(ws + 0x3A0000);      // 32*8*128 f32 = 128 KB
  float* Mg     = (float*)(ws + 0x3C0000);      // 16*128 f32 = 8 KB

  dim3 g1(BPB, NB);
  k_collect<<<g1, 256, 0, stream>>>(x, cand, counts, W1, W2, W3, Mg);
  dim3 g2(8, NB);
  k_selfeat<<<g2, 512, 0, stream>>>(x, cand, counts, Mg, ppart, out);
  k_head<<<NB, 512, 0, stream>>>(ppart, fc1w, fc1b, fc2w, fc2b, out);
}